// Round 6
// baseline (430.946 us; speedup 1.0000x reference)
//
#include <hip/hip_runtime.h>
#include <math.h>

// ---------------------------------------------------------------------------
// SparseMoE — MFMA kernel, MI355X (gfx950).  B=8 S=4096 D=256 F=512 E=8 K=2.
// r15 (from r14 @ 201.9us, k_moe_m 95.7us, MfmaUtil 14.4, 16 waves/CU):
//   * 32-token blocks, 1024 blocks, LDS 38.9KB -> 4 blocks/CU = 32 waves/CU
//     (was 2 blocks/16 waves). Barrier-lockstep phase starvation is the wall
//     (VALU 30% + LDS 32% + L2 ~30% on DIFFERENT pipes, none overlapping);
//     4 independent blocks per CU in arbitrary phases overlap them.
//     Cost: W-frag L2 traffic 2x (~1GB, still XCD-L2-resident: blockIdx&7 =
//     batch pins one batch's 2 experts ~1MB W per XCD).
//   * s_setprio(1) around both MFMA clusters (T5 regime now valid: 4
//     independent blocks/CU -> role diversity for the CU scheduler).
//   Pipeline structure unchanged from r13/r14 (dbuf Hsb, 1 barrier/iter,
//   w2f issued at top, w1f issued one iter ahead, lgkm-only barriers).
// Router fp64 deterministic. ws ~5.3 MB.
// ---------------------------------------------------------------------------

#define B_ 8
#define S_ 4096
#define D_ 256
#define F_ 512
#define E_ 8

typedef short bf16x8 __attribute__((ext_vector_type(8)));
typedef float f32x4 __attribute__((ext_vector_type(4)));

static __device__ __forceinline__ unsigned short f2bf(float f) {
    union { float f; unsigned int i; } v; v.f = f;
    unsigned int x = v.i;
    return (unsigned short)((x + 0x7fffu + ((x >> 16) & 1u)) >> 16);  // RNE
}

// pack two f32 -> two bf16 (RNE), lo = s0, hi = s1
static __device__ __forceinline__ unsigned int cvt_pk_bf16(float s0, float s1) {
    unsigned int r;
    asm("v_cvt_pk_bf16_f32 %0, %1, %2" : "=v"(r) : "v"(s0), "v"(s1));
    return r;
}

// barrier that drains LDS ops only — global loads stay in flight.
static __device__ __forceinline__ void bar_lds() {
    asm volatile("s_waitcnt lgkmcnt(0)" ::: "memory");
    __builtin_amdgcn_s_barrier();
}

// GELU(v) = 0.5 v (1 + erf(v/sqrt2)); erf via A&S 7.1.26, |err|<=1.5e-7.
static __device__ __forceinline__ float gelu_f(float v) {
    float x = fabsf(v) * 0.70710678118654752f;
    float t = __builtin_amdgcn_rcpf(1.0f + 0.3275911f * x);
    float p = t * (0.254829592f +
              t * (-0.284496736f +
              t * (1.421413741f +
              t * (-1.453152027f +
              t * 1.061405429f))));
    float er = 1.0f - p * __expf(-x * x);
    er = __builtin_copysignf(er, v);
    return 0.5f * v * (1.0f + er);
}

// ---------------------------------------------------------------------------
// 1) k_prep: fused grid. Blocks [0,512): fp64 partial mean-reduction over S.
//    Blocks [512,1536): W1 [E][256][512] -> W1T [E][512][256] bf16.
//    Blocks [1536,2560): W2 [E][512][256] -> W2T [E][256][512] bf16.
// ---------------------------------------------------------------------------
__global__ void k_prep(const float* __restrict__ x,
                       double* __restrict__ partial,
                       const float* __restrict__ W1,
                       const float* __restrict__ W2,
                       unsigned short* __restrict__ W1T,
                       unsigned short* __restrict__ W2T) {
    int bid = blockIdx.x;
    if (bid < 512) {
        int b = bid >> 6;
        int c = bid & 63;
        int d = threadIdx.x;
        const float* p = x + ((size_t)(b * S_ + c * 64) * D_ + d);
        double acc = 0.0;
        #pragma unroll 8
        for (int i = 0; i < 64; ++i) acc += (double)p[(size_t)i * D_];
        partial[(size_t)bid * D_ + d] = acc;
        return;
    }
    __shared__ float tile[32][33];
    const float* src;
    unsigned short* dst;
    int R, C, cb, rb;
    if (bid < 1536) {
        int b2 = bid - 512;            // e(8) x by(8) x bx(16)
        int e = b2 >> 7, rem = b2 & 127;
        int by = rem >> 4, bx = rem & 15;
        R = 256; C = 512;
        src = W1 + (size_t)e * R * C;
        dst = W1T + (size_t)e * R * C;
        cb = bx * 32; rb = by * 32;
    } else {
        int b2 = bid - 1536;           // e(8) x by(16) x bx(8)
        int e = b2 >> 7, rem = b2 & 127;
        int by = rem >> 3, bx = rem & 7;
        R = 512; C = 256;
        src = W2 + (size_t)e * R * C;
        dst = W2T + (size_t)e * R * C;
        cb = bx * 32; rb = by * 32;
    }
    int tx = threadIdx.x & 31, ty = threadIdx.x >> 5;
    #pragma unroll
    for (int k = 0; k < 4; ++k)
        tile[ty + 8 * k][tx] = src[(size_t)(rb + ty + 8 * k) * C + cb + tx];
    __syncthreads();
    #pragma unroll
    for (int k = 0; k < 4; ++k)
        dst[(size_t)(cb + ty + 8 * k) * R + rb + tx] = f2bf(tile[tx][ty + 8 * k]);
}

// ---------------------------------------------------------------------------
// 2a) k_red2: 8 blocks (one per batch). Block bb: xs[d] = sum_c partial,
//     then logits lg[bb*8+e] (same fp64 order as before).
// ---------------------------------------------------------------------------
__global__ void k_red2(const double* __restrict__ partial,
                       const float* __restrict__ Wr,
                       const float* __restrict__ br,
                       double* __restrict__ lgout) {
    __shared__ double xs[256];
    int bb = blockIdx.x;
    int t = threadIdx.x;              // 0..255 = d
    double acc = 0.0;
    #pragma unroll 8
    for (int c = 0; c < 64; ++c)
        acc += partial[(size_t)(bb * 64 + c) * D_ + t];
    xs[t] = acc;
    __syncthreads();
    if (t < 8) {
        int e = t;
        double a2 = 0.0;
        for (int d = 0; d < D_; ++d)
            a2 += (xs[d] * (1.0 / (double)S_)) * (double)Wr[d * E_ + e];
        lgout[bb * 8 + e] = a2 + (double)br[e];
    }
}

// ---------------------------------------------------------------------------
// 2b) k_router: 1 tiny block. fp64 phases A/B (unchanged).
// ---------------------------------------------------------------------------
__global__ void k_router(const double* __restrict__ lgin,
                         float* __restrict__ route) {
    __shared__ double lg[64];
    __shared__ double rw[8][8];
    int t = threadIdx.x;
    if (t < 64) lg[t] = lgin[t];
    __syncthreads();
    if (t < 8) {
        int bb = t;
        double m = -1e300;
        for (int ee = 0; ee < 8; ++ee) m = fmax(m, lg[bb * 8 + ee]);
        double s = 0.0;
        double p[8];
        for (int ee = 0; ee < 8; ++ee) { p[ee] = exp(lg[bb * 8 + ee] - m); s += p[ee]; }
        for (int ee = 0; ee < 8; ++ee) rw[bb][ee] = p[ee] / s;
    }
    __syncthreads();
    if (t < 8) {
        int bb = t;
        const double capacity = 5120.0;
        double scale[8];
        for (int ee = 0; ee < 8; ++ee) {
            double load = 0.0;
            for (int b2 = 0; b2 < 8; ++b2) load += rw[b2][ee];
            load *= 4096.0;
            scale[ee] = load > capacity ? capacity / load : 1.0;
        }
        double v[8];
        double m = -1e300;
        for (int ee = 0; ee < 8; ++ee) { v[ee] = rw[bb][ee] * scale[ee]; m = fmax(m, v[ee]); }
        double s = 0.0;
        for (int ee = 0; ee < 8; ++ee) { v[ee] = exp(v[ee] - m); s += v[ee]; }
        for (int ee = 0; ee < 8; ++ee) v[ee] /= s;
        int i1 = 0;
        for (int ee = 1; ee < 8; ++ee) if (v[ee] > v[i1]) i1 = ee;
        int i2 = (i1 == 0) ? 1 : 0;
        for (int ee = 0; ee < 8; ++ee) { if (ee == i1) continue; if (v[ee] > v[i2]) i2 = ee; }
        double d21 = v[i2] - v[i1];
        double ed = exp(d21);
        double w1 = 1.0 / (1.0 + ed);
        double w2 = ed * w1;
        route[bb * 4 + 0] = (float)i1;
        route[bb * 4 + 1] = (float)i2;
        route[bb * 4 + 2] = (float)w1;
        route[bb * 4 + 3] = (float)w2;
    }
}

// ---------------------------------------------------------------------------
// 3) Main MFMA kernel: per block = (batch, 32-token tile). 1024 x 512 thr.
//    8 waves: GEMM1 f-split (wv*16), GEMM2 d-split (wv*32); 2 m-tiles.
//    LDS 38.9KB -> 4 blocks/CU (32 waves). Flattened it=0..7 pipeline:
//      issue w2f_it -> GEMM1 (swapped, w1f from prev it) -> GELU -> Hsb[pb]
//      (b64 stores) -> issue w1f_{it+1} -> lgkm-barrier -> GEMM2.
// ---------------------------------------------------------------------------
__launch_bounds__(512, 8)
__global__ void k_moe_m(const float* __restrict__ xf,
                        const unsigned short* __restrict__ W1T,  // [E][F][D]
                        const unsigned short* __restrict__ W2T,  // [E][D][F]
                        const float* __restrict__ b1,
                        const float* __restrict__ b2,
                        const float* __restrict__ gamma,
                        const float* __restrict__ beta,
                        const float* __restrict__ route,
                        float* __restrict__ out) {
    __shared__ __align__(16) unsigned short Xsb[32][264];     // 16.9 KB
    __shared__ __align__(16) unsigned short Hsb[2][32][136];  // 17.4 KB dbuf
    __shared__ float gbuf[256], bbuf[256];
    __shared__ __align__(16) float rred[32][20];              // LN partials

    const int t = threadIdx.x;        // 0..511
    const int wv = t >> 6;            // wave 0..7
    const int lane = t & 63;
    const int g = lane >> 4;          // quad 0..3
    const int c = lane & 15;          // 0..15
    const int b = blockIdx.x & 7;     // XCD-aligned batch (W L2 locality)
    const int m0 = (blockIdx.x >> 3) * 32;

    if (t < 256) { gbuf[t] = gamma[t]; bbuf[t] = beta[t]; }

    const int e0i = (int)route[b * 4 + 0];
    const int e1i = (int)route[b * 4 + 1];
    const float rw0 = route[b * 4 + 2];
    const float rw1 = route[b * 4 + 3];

    // ---- stage X tile [32][256] as bf16, once (16 d per thread) ----
    {
        int row = t >> 4;
        int col0 = (t & 15) * 16;
        const float* src = xf + ((size_t)(b * S_ + m0 + row) * D_ + col0);
        float4 a0 = *(const float4*)(src + 0);
        float4 a1 = *(const float4*)(src + 4);
        float4 a2 = *(const float4*)(src + 8);
        float4 a3 = *(const float4*)(src + 12);
        union { unsigned int pk[4]; uint4 q; } o0, o1;
        o0.pk[0] = cvt_pk_bf16(a0.x, a0.y);
        o0.pk[1] = cvt_pk_bf16(a0.z, a0.w);
        o0.pk[2] = cvt_pk_bf16(a1.x, a1.y);
        o0.pk[3] = cvt_pk_bf16(a1.z, a1.w);
        o1.pk[0] = cvt_pk_bf16(a2.x, a2.y);
        o1.pk[1] = cvt_pk_bf16(a2.z, a2.w);
        o1.pk[2] = cvt_pk_bf16(a3.x, a3.y);
        o1.pk[3] = cvt_pk_bf16(a3.z, a3.w);
        *(uint4*)&Xsb[row][col0] = o0.q;
        *(uint4*)&Xsb[row][col0 + 8] = o1.q;
    }

    f32x4 Yacc[2][2];
    #pragma unroll
    for (int i = 0; i < 2; ++i)
        #pragma unroll
        for (int j = 0; j < 2; ++j)
            #pragma unroll
            for (int r = 0; r < 4; ++r) Yacc[i][j][r] = 0.f;

    // ---- prologue: issue w1f for it=0 (hidden under staging + barrier) ----
    bf16x8 w1f[8];
    {
        const unsigned short* w1p0 =
            W1T + ((size_t)(e0i * F_ + wv * 16 + c)) * D_ + g * 8;
        #pragma unroll
        for (int kc = 0; kc < 8; ++kc)
            w1f[kc] = *(const bf16x8*)(w1p0 + kc * 32);
    }

    bar_lds();   // Xsb visible to all waves; pins w1f issue

    int pb = 0;
    for (int it = 0; it < 8; ++it) {
        const int sl = it >> 2;
        const int fb = it & 3;
        const int e = sl ? e1i : e0i;
        const float w = sl ? rw1 : rw0;

        // ---- issue w2f for THIS iteration (first use: GEMM2, far below) --
        const unsigned short* w2p =
            W2T + ((size_t)(e * D_ + wv * 32 + c)) * F_ + fb * 128 + g * 8;
        bf16x8 w2f[4][2];
        #pragma unroll
        for (int kc = 0; kc < 4; ++kc)
            #pragma unroll
            for (int nt = 0; nt < 2; ++nt)
                w2f[kc][nt] = *(const bf16x8*)(w2p + (size_t)(nt * 16) * F_ + kc * 32);

        // bias for this lane's 4 consecutive f rows (H^T ownership)
        float4 bias4 = *(const float4*)&b1[e * F_ + fb * 128 + wv * 16 + g * 4];

        // ---- GEMM1 (swapped): H^T[f][token]; lane holds 4 f x 1 token ----
        f32x4 Hacc[2];
        #pragma unroll
        for (int i = 0; i < 2; ++i)
            #pragma unroll
            for (int r = 0; r < 4; ++r) Hacc[i][r] = 0.f;
        __builtin_amdgcn_s_setprio(1);
        #pragma unroll
        for (int kc = 0; kc < 8; ++kc) {
            #pragma unroll
            for (int mt = 0; mt < 2; ++mt) {
                bf16x8 a = *(const bf16x8*)&Xsb[mt * 16 + c][kc * 32 + g * 8];
                Hacc[mt] = __builtin_amdgcn_mfma_f32_16x16x32_bf16(w1f[kc], a, Hacc[mt], 0, 0, 0);
            }
        }
        __builtin_amdgcn_s_setprio(0);

        // ---- GELU(+b1)*w -> Hsb[pb][token][f], ONE b64 store per mt ----
        #pragma unroll
        for (int mt = 0; mt < 2; ++mt) {
            float h0 = w * gelu_f(Hacc[mt][0] + bias4.x);
            float h1 = w * gelu_f(Hacc[mt][1] + bias4.y);
            float h2 = w * gelu_f(Hacc[mt][2] + bias4.z);
            float h3 = w * gelu_f(Hacc[mt][3] + bias4.w);
            uint2 q;
            q.x = cvt_pk_bf16(h0, h1);
            q.y = cvt_pk_bf16(h2, h3);
            *(uint2*)&Hsb[pb][mt * 16 + c][wv * 16 + g * 4] = q;
        }

        // ---- issue w1f for NEXT iteration (hidden under barrier+GEMM2) ----
        {
            const int itn = (it + 1) & 7;
            const int en = (itn >> 2) ? e1i : e0i;
            const int fbn = itn & 3;
            const unsigned short* w1pn =
                W1T + ((size_t)(en * F_ + fbn * 128 + wv * 16 + c)) * D_ + g * 8;
            #pragma unroll
            for (int kc = 0; kc < 8; ++kc)
                w1f[kc] = *(const bf16x8*)(w1pn + kc * 32);
        }

        bar_lds();   // Hsb[pb] visible; all global loads stay in flight

        // ---- GEMM2: Y[32][256] += Hsb[pb] @ w2f ----
        __builtin_amdgcn_s_setprio(1);
        #pragma unroll
        for (int kc = 0; kc < 4; ++kc) {
            #pragma unroll
            for (int mt = 0; mt < 2; ++mt) {
                bf16x8 a = *(const bf16x8*)&Hsb[pb][mt * 16 + c][kc * 32 + g * 8];
                #pragma unroll
                for (int nt = 0; nt < 2; ++nt)
                    Yacc[mt][nt] = __builtin_amdgcn_mfma_f32_16x16x32_bf16(a, w2f[kc][nt], Yacc[mt][nt], 0, 0, 0);
            }
        }
        __builtin_amdgcn_s_setprio(0);
        pb ^= 1;
    }

    // ---- Epilogue: register LayerNorm ----
    // lane holds Y[row][d]: row = mt*16+g*4+r (8 rows), d = wv*32+nt*16+c.
    float bias2[2];
    #pragma unroll
    for (int nt = 0; nt < 2; ++nt) {
        int d = wv * 32 + nt * 16 + c;
        bias2[nt] = rw0 * b2[e0i * D_ + d] + rw1 * b2[e1i * D_ + d];
    }
    #pragma unroll
    for (int mt = 0; mt < 2; ++mt)
        #pragma unroll
        for (int r = 0; r < 4; ++r) {
            int row = mt * 16 + g * 4 + r;
            const float* xr = xf + (size_t)(b * S_ + m0 + row) * D_;
            float s = 0.f, sq = 0.f;
            #pragma unroll
            for (int nt = 0; nt < 2; ++nt) {
                int d = wv * 32 + nt * 16 + c;
                float v = Yacc[mt][nt][r] + bias2[nt] + xr[d];
                Yacc[mt][nt][r] = v;
                s += v; sq += v * v;
            }
            s += __shfl_xor(s, 1); sq += __shfl_xor(sq, 1);
            s += __shfl_xor(s, 2); sq += __shfl_xor(sq, 2);
            s += __shfl_xor(s, 4); sq += __shfl_xor(sq, 4);
            s += __shfl_xor(s, 8); sq += __shfl_xor(sq, 8);
            if (c == 0) { rred[row][wv * 2] = s; rred[row][wv * 2 + 1] = sq; }
        }
    bar_lds();
    #pragma unroll
    for (int mt = 0; mt < 2; ++mt)
        #pragma unroll
        for (int r = 0; r < 4; ++r) {
            int row = mt * 16 + g * 4 + r;
            float4 p0 = *(const float4*)&rred[row][0];
            float4 p1 = *(const float4*)&rred[row][4];
            float4 p2 = *(const float4*)&rred[row][8];
            float4 p3 = *(const float4*)&rred[row][12];
            float s  = ((p0.x + p1.x) + (p2.x + p3.x)) + ((p0.z + p1.z) + (p2.z + p3.z));
            float sq = ((p0.y + p1.y) + (p2.y + p3.y)) + ((p0.w + p1.w) + (p2.w + p3.w));
            float mu = s * (1.0f / 256.0f);
            float var = sq * (1.0f / 256.0f) - mu * mu;
            float rstd = rsqrtf(var + 1e-5f);
            float* op = out + (size_t)(b * S_ + m0 + row) * D_;
            #pragma unroll
            for (int nt = 0; nt < 2; ++nt) {
                int d = wv * 32 + nt * 16 + c;
                op[d] = (Yacc[mt][nt][r] - mu) * rstd * gbuf[d] + bbuf[d];
            }
        }
}

// ---------------------------------------------------------------------------
extern "C" void kernel_launch(void* const* d_in, const int* in_sizes, int n_in,
                              void* d_out, int out_size, void* d_ws, size_t ws_size,
                              hipStream_t stream) {
    const float* x     = (const float*)d_in[0];
    const float* Wr    = (const float*)d_in[1];
    const float* br    = (const float*)d_in[2];
    const float* W1    = (const float*)d_in[3];
    const float* b1    = (const float*)d_in[4];
    const float* W2    = (const float*)d_in[5];
    const float* b2    = (const float*)d_in[6];
    const float* gamma = (const float*)d_in[7];
    const float* beta  = (const float*)d_in[8];
    float* out = (float*)d_out;

    char* ws = (char*)d_ws;
    double* partial = (double*)ws;                               // 1 MB
    float* route  = (float*)(ws + 1064960);                      // 128 B
    double* lg    = (double*)(ws + 1065472);                     // 512 B
    unsigned short* W1T = (unsigned short*)(ws + 1081344);       // 2 MB [E][F][D]
    unsigned short* W2T = (unsigned short*)(ws + 3178496);       // 2 MB [E][D][F]
    // total ws usage: ~5.3 MB

    hipLaunchKernelGGL(k_prep, dim3(2560), dim3(256), 0, stream,
                       x, partial, W1, W2, W1T, W2T);
    hipLaunchKernelGGL(k_red2, dim3(8), dim3(256), 0, stream,
                       partial, Wr, br, lg);
    hipLaunchKernelGGL(k_router, dim3(1), dim3(64), 0, stream,
                       lg, route);
    hipLaunchKernelGGL(k_moe_m, dim3(1024), dim3(512), 0, stream,
                       x, W1T, W2T, b1, b2, gamma, beta, route, out);
}

// Round 7
// 209.082 us; speedup vs baseline: 2.0611x; 2.0611x over previous
//
#include <hip/hip_runtime.h>
#include <math.h>

// ---------------------------------------------------------------------------
// SparseMoE — MFMA kernel, MI355X (gfx950).  B=8 S=4096 D=256 F=512 E=8 K=2.
// r16 (from r14 @ 201.9us; r15 occupancy attempt FAILED — launch_bounds(512,8)
// capped 64 VGPR/wave -> full spill, 739MB scratch writes, 320us):
//   * Back to r14 geometry: 64-token blocks, 512 x 512thr, 2 blocks/CU.
//   * Deferred-GEMM2 pipeline: body(it) = GEMM1(it) -> {GELU(it) || GEMM2(it-1)}
//     chunk-interleaved. GELU (VALU) and GEMM2 (LDS+MFMA) are independent ->
//     co-issue collapses the serial phase structure (r14 counters: VALU 30%
//     + LDS 31% + MFMA 14% summed to the wall = pure phase serialization).
//     GEMM2(it-1) reads Hsb written two barriers ago: zero wait on its reads.
//   * Accumulation order per Yacc element IDENTICAL to r14 (same it/kc/mt/nt
//     sequence) -> bit-identical output.
// Router fp64 deterministic. ws ~5.3 MB.
// ---------------------------------------------------------------------------

#define B_ 8
#define S_ 4096
#define D_ 256
#define F_ 512
#define E_ 8

typedef short bf16x8 __attribute__((ext_vector_type(8)));
typedef float f32x4 __attribute__((ext_vector_type(4)));

static __device__ __forceinline__ unsigned short f2bf(float f) {
    union { float f; unsigned int i; } v; v.f = f;
    unsigned int x = v.i;
    return (unsigned short)((x + 0x7fffu + ((x >> 16) & 1u)) >> 16);  // RNE
}

// pack two f32 -> two bf16 (RNE), lo = s0, hi = s1
static __device__ __forceinline__ unsigned int cvt_pk_bf16(float s0, float s1) {
    unsigned int r;
    asm("v_cvt_pk_bf16_f32 %0, %1, %2" : "=v"(r) : "v"(s0), "v"(s1));
    return r;
}

// barrier that drains LDS ops only — global loads stay in flight.
static __device__ __forceinline__ void bar_lds() {
    asm volatile("s_waitcnt lgkmcnt(0)" ::: "memory");
    __builtin_amdgcn_s_barrier();
}

// GELU(v) = 0.5 v (1 + erf(v/sqrt2)); erf via A&S 7.1.26, |err|<=1.5e-7.
static __device__ __forceinline__ float gelu_f(float v) {
    float x = fabsf(v) * 0.70710678118654752f;
    float t = __builtin_amdgcn_rcpf(1.0f + 0.3275911f * x);
    float p = t * (0.254829592f +
              t * (-0.284496736f +
              t * (1.421413741f +
              t * (-1.453152027f +
              t * 1.061405429f))));
    float er = 1.0f - p * __expf(-x * x);
    er = __builtin_copysignf(er, v);
    return 0.5f * v * (1.0f + er);
}

// ---------------------------------------------------------------------------
// 1) k_prep: fused grid. Blocks [0,512): fp64 partial mean-reduction over S.
//    Blocks [512,1536): W1 [E][256][512] -> W1T [E][512][256] bf16.
//    Blocks [1536,2560): W2 [E][512][256] -> W2T [E][256][512] bf16.
// ---------------------------------------------------------------------------
__global__ void k_prep(const float* __restrict__ x,
                       double* __restrict__ partial,
                       const float* __restrict__ W1,
                       const float* __restrict__ W2,
                       unsigned short* __restrict__ W1T,
                       unsigned short* __restrict__ W2T) {
    int bid = blockIdx.x;
    if (bid < 512) {
        int b = bid >> 6;
        int c = bid & 63;
        int d = threadIdx.x;
        const float* p = x + ((size_t)(b * S_ + c * 64) * D_ + d);
        double acc = 0.0;
        #pragma unroll 8
        for (int i = 0; i < 64; ++i) acc += (double)p[(size_t)i * D_];
        partial[(size_t)bid * D_ + d] = acc;
        return;
    }
    __shared__ float tile[32][33];
    const float* src;
    unsigned short* dst;
    int R, C, cb, rb;
    if (bid < 1536) {
        int b2 = bid - 512;            // e(8) x by(8) x bx(16)
        int e = b2 >> 7, rem = b2 & 127;
        int by = rem >> 4, bx = rem & 15;
        R = 256; C = 512;
        src = W1 + (size_t)e * R * C;
        dst = W1T + (size_t)e * R * C;
        cb = bx * 32; rb = by * 32;
    } else {
        int b2 = bid - 1536;           // e(8) x by(16) x bx(8)
        int e = b2 >> 7, rem = b2 & 127;
        int by = rem >> 3, bx = rem & 7;
        R = 512; C = 256;
        src = W2 + (size_t)e * R * C;
        dst = W2T + (size_t)e * R * C;
        cb = bx * 32; rb = by * 32;
    }
    int tx = threadIdx.x & 31, ty = threadIdx.x >> 5;
    #pragma unroll
    for (int k = 0; k < 4; ++k)
        tile[ty + 8 * k][tx] = src[(size_t)(rb + ty + 8 * k) * C + cb + tx];
    __syncthreads();
    #pragma unroll
    for (int k = 0; k < 4; ++k)
        dst[(size_t)(cb + ty + 8 * k) * R + rb + tx] = f2bf(tile[tx][ty + 8 * k]);
}

// ---------------------------------------------------------------------------
// 2a) k_red2: 8 blocks (one per batch). Block bb: xs[d] = sum_c partial,
//     then logits lg[bb*8+e] (same fp64 order as before).
// ---------------------------------------------------------------------------
__global__ void k_red2(const double* __restrict__ partial,
                       const float* __restrict__ Wr,
                       const float* __restrict__ br,
                       double* __restrict__ lgout) {
    __shared__ double xs[256];
    int bb = blockIdx.x;
    int t = threadIdx.x;              // 0..255 = d
    double acc = 0.0;
    #pragma unroll 8
    for (int c = 0; c < 64; ++c)
        acc += partial[(size_t)(bb * 64 + c) * D_ + t];
    xs[t] = acc;
    __syncthreads();
    if (t < 8) {
        int e = t;
        double a2 = 0.0;
        for (int d = 0; d < D_; ++d)
            a2 += (xs[d] * (1.0 / (double)S_)) * (double)Wr[d * E_ + e];
        lgout[bb * 8 + e] = a2 + (double)br[e];
    }
}

// ---------------------------------------------------------------------------
// 2b) k_router: 1 tiny block. fp64 phases A/B (unchanged).
// ---------------------------------------------------------------------------
__global__ void k_router(const double* __restrict__ lgin,
                         float* __restrict__ route) {
    __shared__ double lg[64];
    __shared__ double rw[8][8];
    int t = threadIdx.x;
    if (t < 64) lg[t] = lgin[t];
    __syncthreads();
    if (t < 8) {
        int bb = t;
        double m = -1e300;
        for (int ee = 0; ee < 8; ++ee) m = fmax(m, lg[bb * 8 + ee]);
        double s = 0.0;
        double p[8];
        for (int ee = 0; ee < 8; ++ee) { p[ee] = exp(lg[bb * 8 + ee] - m); s += p[ee]; }
        for (int ee = 0; ee < 8; ++ee) rw[bb][ee] = p[ee] / s;
    }
    __syncthreads();
    if (t < 8) {
        int bb = t;
        const double capacity = 5120.0;
        double scale[8];
        for (int ee = 0; ee < 8; ++ee) {
            double load = 0.0;
            for (int b2 = 0; b2 < 8; ++b2) load += rw[b2][ee];
            load *= 4096.0;
            scale[ee] = load > capacity ? capacity / load : 1.0;
        }
        double v[8];
        double m = -1e300;
        for (int ee = 0; ee < 8; ++ee) { v[ee] = rw[bb][ee] * scale[ee]; m = fmax(m, v[ee]); }
        double s = 0.0;
        for (int ee = 0; ee < 8; ++ee) { v[ee] = exp(v[ee] - m); s += v[ee]; }
        for (int ee = 0; ee < 8; ++ee) v[ee] /= s;
        int i1 = 0;
        for (int ee = 1; ee < 8; ++ee) if (v[ee] > v[i1]) i1 = ee;
        int i2 = (i1 == 0) ? 1 : 0;
        for (int ee = 0; ee < 8; ++ee) { if (ee == i1) continue; if (v[ee] > v[i2]) i2 = ee; }
        double d21 = v[i2] - v[i1];
        double ed = exp(d21);
        double w1 = 1.0 / (1.0 + ed);
        double w2 = ed * w1;
        route[bb * 4 + 0] = (float)i1;
        route[bb * 4 + 1] = (float)i2;
        route[bb * 4 + 2] = (float)w1;
        route[bb * 4 + 3] = (float)w2;
    }
}

// ---------------------------------------------------------------------------
// 3) Main MFMA kernel: per block = (batch, 64-token tile). 512 x 512 thr.
//    Deferred-GEMM2 pipeline, it = 0..7 (sl=it>>2, fb=it&3):
//      body(it): [issue w2f(it-1)] -> GEMM1(it) w/ w1f(it) ->
//                {GELU(it)->Hsb[it&1]  ||  GEMM2(it-1) from Hsb[(it-1)&1]}
//                interleaved by chunk -> issue w1f(it+1) (it=7: w2f(7)) ->
//                lgkm-barrier.
//      epilogue: GEMM2(7), then register LayerNorm.
// ---------------------------------------------------------------------------
__launch_bounds__(512, 4)
__global__ void k_moe_m(const float* __restrict__ xf,
                        const unsigned short* __restrict__ W1T,  // [E][F][D]
                        const unsigned short* __restrict__ W2T,  // [E][D][F]
                        const float* __restrict__ b1,
                        const float* __restrict__ b2,
                        const float* __restrict__ gamma,
                        const float* __restrict__ beta,
                        const float* __restrict__ route,
                        float* __restrict__ out) {
    __shared__ __align__(16) unsigned short Xsb[64][264];     // 33.8 KB
    __shared__ __align__(16) unsigned short Hsb[2][64][136];  // 34.8 KB dbuf
    __shared__ float gbuf[256], bbuf[256];
    __shared__ __align__(16) float rred[64][20];              // LN partials

    const int t = threadIdx.x;        // 0..511
    const int wv = t >> 6;            // wave 0..7
    const int lane = t & 63;
    const int g = lane >> 4;          // quad 0..3
    const int c = lane & 15;          // 0..15
    const int b = blockIdx.x & 7;     // XCD-aligned batch (W L2 locality)
    const int m0 = (blockIdx.x >> 3) * 64;

    if (t < 256) { gbuf[t] = gamma[t]; bbuf[t] = beta[t]; }

    const int e0i = (int)route[b * 4 + 0];
    const int e1i = (int)route[b * 4 + 1];
    const float rw0 = route[b * 4 + 2];
    const float rw1 = route[b * 4 + 3];

    // ---- stage X tile [64][256] as bf16, once ----
    {
        int row = t >> 3;
        int col0 = (t & 7) * 32;
        const float* src = xf + ((size_t)(b * S_ + m0 + row) * D_ + col0);
        #pragma unroll
        for (int jg = 0; jg < 4; ++jg) {
            float4 a0 = *(const float4*)(src + jg * 8);
            float4 a1 = *(const float4*)(src + jg * 8 + 4);
            union { unsigned int pk[4]; uint4 q; } o;
            o.pk[0] = cvt_pk_bf16(a0.x, a0.y);
            o.pk[1] = cvt_pk_bf16(a0.z, a0.w);
            o.pk[2] = cvt_pk_bf16(a1.x, a1.y);
            o.pk[3] = cvt_pk_bf16(a1.z, a1.w);
            *(uint4*)&Xsb[row][col0 + jg * 8] = o.q;
        }
    }

    f32x4 Yacc[4][2];
    #pragma unroll
    for (int i = 0; i < 4; ++i)
        #pragma unroll
        for (int j = 0; j < 2; ++j)
            #pragma unroll
            for (int r = 0; r < 4; ++r) Yacc[i][j][r] = 0.f;

    // ---- prologue: issue w1f for it=0 ----
    bf16x8 w1f[8];
    {
        const unsigned short* w1p0 =
            W1T + ((size_t)(e0i * F_ + wv * 16 + c)) * D_ + g * 8;
        #pragma unroll
        for (int kc = 0; kc < 8; ++kc)
            w1f[kc] = *(const bf16x8*)(w1p0 + kc * 32);
    }

    bar_lds();   // Xsb visible to all waves; pins w1f issue

    bf16x8 w2f[4][2];   // fragments for GEMM2(it-1), loaded at body top

    // ================== body(0): GEMM1(0) + GELU(0), no GEMM2 ==============
    {
        float4 bias4 = *(const float4*)&b1[e0i * F_ + wv * 16 + g * 4];
        f32x4 Hacc[4];
        #pragma unroll
        for (int i = 0; i < 4; ++i)
            #pragma unroll
            for (int r = 0; r < 4; ++r) Hacc[i][r] = 0.f;
        #pragma unroll
        for (int kc = 0; kc < 8; ++kc) {
            #pragma unroll
            for (int mt = 0; mt < 4; ++mt) {
                bf16x8 a = *(const bf16x8*)&Xsb[mt * 16 + c][kc * 32 + g * 8];
                Hacc[mt] = __builtin_amdgcn_mfma_f32_16x16x32_bf16(w1f[kc], a, Hacc[mt], 0, 0, 0);
            }
        }
        #pragma unroll
        for (int mt = 0; mt < 4; ++mt) {
            float h0 = rw0 * gelu_f(Hacc[mt][0] + bias4.x);
            float h1 = rw0 * gelu_f(Hacc[mt][1] + bias4.y);
            float h2 = rw0 * gelu_f(Hacc[mt][2] + bias4.z);
            float h3 = rw0 * gelu_f(Hacc[mt][3] + bias4.w);
            uint2 q;
            q.x = cvt_pk_bf16(h0, h1);
            q.y = cvt_pk_bf16(h2, h3);
            *(uint2*)&Hsb[0][mt * 16 + c][wv * 16 + g * 4] = q;
        }
        // issue w1f(1)
        const unsigned short* w1pn =
            W1T + ((size_t)(e0i * F_ + 128 + wv * 16 + c)) * D_ + g * 8;
        #pragma unroll
        for (int kc = 0; kc < 8; ++kc)
            w1f[kc] = *(const bf16x8*)(w1pn + kc * 32);
        bar_lds();
    }

    // ================== bodies 1..7 ==================
    for (int it = 1; it < 8; ++it) {
        const int e  = (it >= 4) ? e1i : e0i;
        const float w = (it >= 4) ? rw1 : rw0;
        const int fb = it & 3;
        const int ep  = ((it - 1) >= 4) ? e1i : e0i;
        const int fbp = (it - 1) & 3;
        const int wb = it & 1;          // write buffer; read buffer = wb^1

        // ---- issue w2f(it-1) (first use: after GEMM1 + first GELU chunk) --
        const unsigned short* w2p =
            W2T + ((size_t)(ep * D_ + wv * 32 + c)) * F_ + fbp * 128 + g * 8;
        #pragma unroll
        for (int kc = 0; kc < 4; ++kc)
            #pragma unroll
            for (int nt = 0; nt < 2; ++nt)
                w2f[kc][nt] = *(const bf16x8*)(w2p + (size_t)(nt * 16) * F_ + kc * 32);

        float4 bias4 = *(const float4*)&b1[e * F_ + fb * 128 + wv * 16 + g * 4];

        // ---- GEMM1(it) ----
        f32x4 Hacc[4];
        #pragma unroll
        for (int i = 0; i < 4; ++i)
            #pragma unroll
            for (int r = 0; r < 4; ++r) Hacc[i][r] = 0.f;
        #pragma unroll
        for (int kc = 0; kc < 8; ++kc) {
            #pragma unroll
            for (int mt = 0; mt < 4; ++mt) {
                bf16x8 a = *(const bf16x8*)&Xsb[mt * 16 + c][kc * 32 + g * 8];
                Hacc[mt] = __builtin_amdgcn_mfma_f32_16x16x32_bf16(w1f[kc], a, Hacc[mt], 0, 0, 0);
            }
        }

        // ---- {GELU(it) || GEMM2(it-1)} chunk-interleave (u = mt = kc) ----
        #pragma unroll
        for (int u = 0; u < 4; ++u) {
            // B-chunk: GELU mt=u -> Hsb[wb]
            {
                float h0 = w * gelu_f(Hacc[u][0] + bias4.x);
                float h1 = w * gelu_f(Hacc[u][1] + bias4.y);
                float h2 = w * gelu_f(Hacc[u][2] + bias4.z);
                float h3 = w * gelu_f(Hacc[u][3] + bias4.w);
                uint2 q;
                q.x = cvt_pk_bf16(h0, h1);
                q.y = cvt_pk_bf16(h2, h3);
                *(uint2*)&Hsb[wb][u * 16 + c][wv * 16 + g * 4] = q;
            }
            // C-chunk: GEMM2(it-1) kc=u, reads Hsb[wb^1] (two barriers old)
            #pragma unroll
            for (int mt = 0; mt < 4; ++mt) {
                bf16x8 a = *(const bf16x8*)&Hsb[wb ^ 1][mt * 16 + c][u * 32 + g * 8];
                #pragma unroll
                for (int nt = 0; nt < 2; ++nt)
                    Yacc[mt][nt] = __builtin_amdgcn_mfma_f32_16x16x32_bf16(a, w2f[u][nt], Yacc[mt][nt], 0, 0, 0);
            }
        }

        // ---- pre-barrier issue: w1f(it+1), or w2f(7) on the last body ----
        if (it < 7) {
            const int itn = it + 1;
            const int en = (itn >= 4) ? e1i : e0i;
            const int fbn = itn & 3;
            const unsigned short* w1pn =
                W1T + ((size_t)(en * F_ + fbn * 128 + wv * 16 + c)) * D_ + g * 8;
            #pragma unroll
            for (int kc = 0; kc < 8; ++kc)
                w1f[kc] = *(const bf16x8*)(w1pn + kc * 32);
        } else {
            const unsigned short* w2p7 =
                W2T + ((size_t)(e1i * D_ + wv * 32 + c)) * F_ + 3 * 128 + g * 8;
            #pragma unroll
            for (int kc = 0; kc < 4; ++kc)
                #pragma unroll
                for (int nt = 0; nt < 2; ++nt)
                    w2f[kc][nt] = *(const bf16x8*)(w2p7 + (size_t)(nt * 16) * F_ + kc * 32);
        }

        bar_lds();   // Hsb[wb] visible; global loads stay in flight
    }

    // ================== epilogue GEMM2(7): reads Hsb[1] ==================
    #pragma unroll
    for (int kc = 0; kc < 4; ++kc) {
        #pragma unroll
        for (int mt = 0; mt < 4; ++mt) {
            bf16x8 a = *(const bf16x8*)&Hsb[1][mt * 16 + c][kc * 32 + g * 8];
            #pragma unroll
            for (int nt = 0; nt < 2; ++nt)
                Yacc[mt][nt] = __builtin_amdgcn_mfma_f32_16x16x32_bf16(a, w2f[kc][nt], Yacc[mt][nt], 0, 0, 0);
        }
    }

    // ---- Epilogue: register LayerNorm ----
    // lane holds Y[row][d]: row = mt*16+g*4+r (16 rows), d = wv*32+nt*16+c.
    float bias2[2];
    #pragma unroll
    for (int nt = 0; nt < 2; ++nt) {
        int d = wv * 32 + nt * 16 + c;
        bias2[nt] = rw0 * b2[e0i * D_ + d] + rw1 * b2[e1i * D_ + d];
    }
    #pragma unroll
    for (int mt = 0; mt < 4; ++mt)
        #pragma unroll
        for (int r = 0; r < 4; ++r) {
            int row = mt * 16 + g * 4 + r;
            const float* xr = xf + (size_t)(b * S_ + m0 + row) * D_;
            float s = 0.f, sq = 0.f;
            #pragma unroll
            for (int nt = 0; nt < 2; ++nt) {
                int d = wv * 32 + nt * 16 + c;
                float v = Yacc[mt][nt][r] + bias2[nt] + xr[d];
                Yacc[mt][nt][r] = v;
                s += v; sq += v * v;
            }
            s += __shfl_xor(s, 1); sq += __shfl_xor(sq, 1);
            s += __shfl_xor(s, 2); sq += __shfl_xor(sq, 2);
            s += __shfl_xor(s, 4); sq += __shfl_xor(sq, 4);
            s += __shfl_xor(s, 8); sq += __shfl_xor(sq, 8);
            if (c == 0) { rred[row][wv * 2] = s; rred[row][wv * 2 + 1] = sq; }
        }
    bar_lds();
    #pragma unroll
    for (int mt = 0; mt < 4; ++mt)
        #pragma unroll
        for (int r = 0; r < 4; ++r) {
            int row = mt * 16 + g * 4 + r;
            float4 p0 = *(const float4*)&rred[row][0];
            float4 p1 = *(const float4*)&rred[row][4];
            float4 p2 = *(const float4*)&rred[row][8];
            float4 p3 = *(const float4*)&rred[row][12];
            float s  = ((p0.x + p1.x) + (p2.x + p3.x)) + ((p0.z + p1.z) + (p2.z + p3.z));
            float sq = ((p0.y + p1.y) + (p2.y + p3.y)) + ((p0.w + p1.w) + (p2.w + p3.w));
            float mu = s * (1.0f / 256.0f);
            float var = sq * (1.0f / 256.0f) - mu * mu;
            float rstd = rsqrtf(var + 1e-5f);
            float* op = out + (size_t)(b * S_ + m0 + row) * D_;
            #pragma unroll
            for (int nt = 0; nt < 2; ++nt) {
                int d = wv * 32 + nt * 16 + c;
                op[d] = (Yacc[mt][nt][r] - mu) * rstd * gbuf[d] + bbuf[d];
            }
        }
}

// ---------------------------------------------------------------------------
extern "C" void kernel_launch(void* const* d_in, const int* in_sizes, int n_in,
                              void* d_out, int out_size, void* d_ws, size_t ws_size,
                              hipStream_t stream) {
    const float* x     = (const float*)d_in[0];
    const float* Wr    = (const float*)d_in[1];
    const float* br    = (const float*)d_in[2];
    const float* W1    = (const float*)d_in[3];
    const float* b1    = (const float*)d_in[4];
    const float* W2    = (const float*)d_in[5];
    const float* b2    = (const float*)d_in[6];
    const float* gamma = (const float*)d_in[7];
    const float* beta  = (const float*)d_in[8];
    float* out = (float*)d_out;

    char* ws = (char*)d_ws;
    double* partial = (double*)ws;                               // 1 MB
    float* route  = (float*)(ws + 1064960);                      // 128 B
    double* lg    = (double*)(ws + 1065472);                     // 512 B
    unsigned short* W1T = (unsigned short*)(ws + 1081344);       // 2 MB [E][F][D]
    unsigned short* W2T = (unsigned short*)(ws + 3178496);       // 2 MB [E][D][F]
    // total ws usage: ~5.3 MB

    hipLaunchKernelGGL(k_prep, dim3(2560), dim3(256), 0, stream,
                       x, partial, W1, W2, W1T, W2T);
    hipLaunchKernelGGL(k_red2, dim3(8), dim3(256), 0, stream,
                       partial, Wr, br, lg);
    hipLaunchKernelGGL(k_router, dim3(1), dim3(64), 0, stream,
                       lg, route);
    hipLaunchKernelGGL(k_moe_m, dim3(512), dim3(512), 0, stream,
                       x, W1T, W2T, b1, b2, gamma, beta, route, out);
}